// Round 3
// baseline (1035.429 us; speedup 1.0000x reference)
//
#include <hip/hip_runtime.h>

#define NPTS   8192
#define NBATCH 16
#define NGROUP 512
#define GSIZE  32
#define BIGF   1e10f

// ---------------------------------------------------------------------------
// Kernel 1: farthest point sampling. One block per batch, 512 threads
// (8 waves), 16 points per thread in registers; coords also in LDS planes for
// the broadcast read of the last-selected point. fp32 difference-form distance
// (verified exact: center output passes). Tie-break = first max (lower idx).
// ---------------------------------------------------------------------------
__global__ __launch_bounds__(512) void fps_kernel(const float* __restrict__ pc,
                                                  int* __restrict__ rep) {
    const int b    = blockIdx.x;
    const int t    = threadIdx.x;
    const int lane = t & 63;
    const int w    = t >> 6;

    __shared__ float sx[NPTS], sy[NPTS], sz[NPTS];   // 96 KB
    __shared__ float rv[2][8];
    __shared__ int   ri[2][8];

    const float* base = pc + (size_t)b * NPTS * 6;

    float px[16], py[16], pz[16], dmin[16];
#pragma unroll
    for (int j = 0; j < 16; ++j) {
        const int p = t * 16 + j;
        const float x = base[p * 6 + 0];
        const float y = base[p * 6 + 1];
        const float z = base[p * 6 + 2];
        px[j] = x; py[j] = y; pz[j] = z;
        sx[p] = x; sy[p] = y; sz[p] = z;
        dmin[j] = BIGF;
    }
    __syncthreads();

    int last = 0;
    for (int k = 0; k < NGROUP; ++k) {
        if (t == 0) rep[b * NGROUP + k] = last;
        if (k == NGROUP - 1) break;

        const float lx = sx[last];
        const float ly = sy[last];
        const float lz = sz[last];

        float bv = -1.0f;
        int   bi = 0;
#pragma unroll
        for (int j = 0; j < 16; ++j) {
            const float dx = __fsub_rn(px[j], lx);
            const float dy = __fsub_rn(py[j], ly);
            const float dz = __fsub_rn(pz[j], lz);
            const float d = __fadd_rn(__fadd_rn(__fmul_rn(dx, dx),
                                                __fmul_rn(dy, dy)),
                                      __fmul_rn(dz, dz));
            const float dm = fminf(dmin[j], d);
            dmin[j] = dm;
            if (dm > bv) { bv = dm; bi = t * 16 + j; }
        }

#pragma unroll
        for (int off = 1; off < 64; off <<= 1) {
            const float ov = __shfl_xor(bv, off);
            const int   oi = __shfl_xor(bi, off);
            if (ov > bv || (ov == bv && oi < bi)) { bv = ov; bi = oi; }
        }

        const int buf = k & 1;           // parity double-buffer -> 1 barrier/iter
        if (lane == 0) { rv[buf][w] = bv; ri[buf][w] = bi; }
        __syncthreads();

        float gbv = rv[buf][0];
        int   gbi = ri[buf][0];
#pragma unroll
        for (int ww = 1; ww < 8; ++ww) {
            const float v = rv[buf][ww];
            const int   i = ri[buf][ww];
            if (v > gbv || (v == gbv && i < gbi)) { gbv = v; gbi = i; }
        }
        last = gbi;
    }
}

// ---------------------------------------------------------------------------
// Kernel 2: 32-NN per sampled center + gathers.
// One wave per query. Top-32 kept as a lane-distributed sorted list
// (lane l = rank l). d2 computed in FLOAT64 DIFFERENCE FORM: fp32 inputs are
// exact in fp64 and the difference form has no cancellation, so the ranking
// equals the true mathematical ranking (robust to whichever fp32 rounding the
// reference pipeline used; near-ties at the 1e-6 level are resolved truly).
// Index tie-break = lower index first (lax.top_k stability).
// ---------------------------------------------------------------------------
__global__ __launch_bounds__(256) void knn_kernel(const float* __restrict__ pc,
                                                  const int* __restrict__ rep,
                                                  float* __restrict__ out) {
    const int tid  = threadIdx.x;
    const int lane = tid & 63;
    const int w    = tid >> 6;
    const int q    = blockIdx.x * 4 + w;       // 0 .. 8191
    const int b    = q >> 9;

    const float* base = pc + (size_t)b * NPTS * 6;
    const int    r    = rep[q];

    const float qxf = base[r * 6 + 0];
    const float qyf = base[r * 6 + 1];
    const float qzf = base[r * 6 + 2];
    const double qx = (double)qxf, qy = (double)qyf, qz = (double)qzf;

    const double DINF = __longlong_as_double(0x7ff0000000000000LL);
    double vd = DINF;  int vi = 0x7fffffff;    // distributed sorted list entry
    double taud = DINF; int taui = 0x7fffffff; // current 32nd element (lane 31)

    for (int i = 0; i < NPTS / 64; ++i) {
        const int p = i * 64 + lane;
        const double dx = qx - (double)base[p * 6 + 0];
        const double dy = qy - (double)base[p * 6 + 1];
        const double dz = qz - (double)base[p * 6 + 2];
        const double d2 = dx * dx + dy * dy + dz * dz;   // no cancellation

        const bool acc = (d2 < taud) || (d2 == taud && p < taui);
        unsigned long long mask = __ballot(acc);
        while (mask) {
            const int l = __ffsll(mask) - 1;
            mask &= mask - 1;
            const double xd = __shfl(d2, l);
            const int    xi = __shfl(p, l);
            const double pd = __shfl_up(vd, 1);
            const int    pi = __shfl_up(vi, 1);
            const bool ltp = (lane > 0) && ((xd < pd) || (xd == pd && xi < pi));
            const bool ltc = (xd < vd) || (xd == vd && xi < vi);
            const double nvd = ltp ? pd : (ltc ? xd : vd);
            const int    nvi = ltp ? pi : (ltc ? xi : vi);
            vd = nvd; vi = nvi;
        }
        taud = __shfl(vd, 31);
        taui = __shfl(vi, 31);
    }

    // ---- outputs ----
    const size_t NBH = (size_t)NBATCH * NGROUP * GSIZE * 6;   // neighborhood elems
    const size_t CEN = (size_t)NBATCH * NGROUP * 6;           // center elems

    if (lane == 0) {
#pragma unroll
        for (int c = 0; c < 6; ++c)
            out[NBH + (size_t)q * 6 + c] = base[r * 6 + c];
    }
    if (lane < GSIZE) {
        const int n = vi;                      // lane-sorted: position == lane
        out[NBH + CEN + (size_t)q * GSIZE + lane] = (float)n;

        const float* np_ = base + (size_t)n * 6;
        const size_t o = ((size_t)q * GSIZE + lane) * 6;
        out[o + 0] = __fsub_rn(np_[0], qxf);
        out[o + 1] = __fsub_rn(np_[1], qyf);
        out[o + 2] = __fsub_rn(np_[2], qzf);
        out[o + 3] = np_[3];
        out[o + 4] = np_[4];
        out[o + 5] = np_[5];
    }
}

extern "C" void kernel_launch(void* const* d_in, const int* in_sizes, int n_in,
                              void* d_out, int out_size, void* d_ws, size_t ws_size,
                              hipStream_t stream) {
    const float* pc  = (const float*)d_in[0];
    float*       out = (float*)d_out;
    int*         rep = (int*)d_ws;             // 16*512 ints = 32 KB scratch

    fps_kernel<<<NBATCH, 512, 0, stream>>>(pc, rep);
    knn_kernel<<<(NBATCH * NGROUP) / 4, 256, 0, stream>>>(pc, rep, out);
}

// Round 5
// 759.111 us; speedup vs baseline: 1.3640x; 1.3640x over previous
//
#include <hip/hip_runtime.h>

#define NPTS   8192
#define NBATCH 16
#define NGROUP 512
#define GSIZE  32
#define BIGF   1e10f

// DPP-assisted max: x = max(x, x shifted by dpp ctrl). CTRL must be an ICE,
// hence the template parameter. Values are >= 0 here, so bound_ctrl=true
// (OOB lanes read 0) is a no-op for max.
template <int CTRL>
__device__ __forceinline__ float dpp_max(float x) {
    const int s = __builtin_amdgcn_update_dpp(0, __float_as_int(x), CTRL, 0xF, 0xF, true);
    return fmaxf(x, __int_as_float(s));
}

// ---------------------------------------------------------------------------
// Kernel 1: farthest point sampling. One block per batch, 512 threads
// (8 waves), 16 points per thread in registers; coords in LDS float4 for the
// broadcast read of the selected point.
// Wave argmax: DPP v_max chain (row_shr 1/2/4/8, row_bcast 15/31) for the
// VALUE, then ballot + one shfl for the INDEX (lane order is index-monotone,
// so first winning lane = lowest index -> matches jnp.argmax tie-break).
// Cross-wave: packed u64 keys (dist_bits<<13)|(8191-idx) -> max = argmax with
// lowest-index tie-break.
// ---------------------------------------------------------------------------
__global__ __launch_bounds__(512) void fps_kernel(const float* __restrict__ pc,
                                                  int* __restrict__ rep) {
    const int b    = blockIdx.x;
    const int t    = threadIdx.x;
    const int lane = t & 63;
    const int w    = t >> 6;

    __shared__ float4 sp[NPTS];                      // 128 KB
    __shared__ unsigned long long keys[2][8];

    const float* base = pc + (size_t)b * NPTS * 6;

    float px[16], py[16], pz[16], dmin[16];
#pragma unroll
    for (int j = 0; j < 16; ++j) {
        const int p = t * 16 + j;
        const float x = base[p * 6 + 0];
        const float y = base[p * 6 + 1];
        const float z = base[p * 6 + 2];
        px[j] = x; py[j] = y; pz[j] = z;
        sp[p] = make_float4(x, y, z, 0.0f);
        dmin[j] = BIGF;
    }
    __syncthreads();

    int last = 0;
    for (int k = 0; k < NGROUP; ++k) {
        if (t == 0) rep[b * NGROUP + k] = last;
        if (k == NGROUP - 1) break;

        const float4 L = sp[last];                   // one ds_read_b128, broadcast

        float bv = -1.0f;
        int   bi = 0;
#pragma unroll
        for (int j = 0; j < 16; ++j) {
            const float dx = __fsub_rn(px[j], L.x);
            const float dy = __fsub_rn(py[j], L.y);
            const float dz = __fsub_rn(pz[j], L.z);
            // ((dx^2 + dy^2) + dz^2), no FMA -> matches numpy fp32 (verified)
            const float d = __fadd_rn(__fadd_rn(__fmul_rn(dx, dx),
                                                __fmul_rn(dy, dy)),
                                      __fmul_rn(dz, dz));
            const float dm = fminf(dmin[j], d);
            dmin[j] = dm;
            if (dm > bv) { bv = dm; bi = t * 16 + j; }   // strict > keeps lowest idx
        }

        // wave max of bv via DPP (VALU-only, ~6 dependent v_max)
        float m = bv;
        m = dpp_max<0x111>(m);   // row_shr:1
        m = dpp_max<0x112>(m);   // row_shr:2
        m = dpp_max<0x114>(m);   // row_shr:4
        m = dpp_max<0x118>(m);   // row_shr:8  -> lane 15/31/47/63 = row max
        m = dpp_max<0x142>(m);   // row_bcast:15 -> lane 31/63 = half max
        m = dpp_max<0x143>(m);   // row_bcast:31 -> lane 63 = wave max
        const float wmax = __shfl(m, 63);

        const unsigned long long msk = __ballot(bv == wmax);
        const int l   = __ffsll(msk) - 1;            // lowest winning lane
        const int wbi = __shfl(bi, l);               // its index (lowest overall)

        const int buf = k & 1;                       // parity dbuf -> 1 barrier/iter
        if (lane == 0)
            keys[buf][w] = ((unsigned long long)__float_as_uint(wmax) << 13)
                         | (unsigned int)(8191 - wbi);
        __syncthreads();

        unsigned long long best = keys[buf][0];
#pragma unroll
        for (int ww = 1; ww < 8; ++ww) {
            const unsigned long long kk = keys[buf][ww];
            if (kk > best) best = kk;                // ties impossible (distinct idx)
        }
        last = 8191 - (int)(best & 0x1FFFull);
    }
}

// ---------------------------------------------------------------------------
// Kernel 2: 32-NN per sampled center + gathers. 1024 threads = 16 waves =
// 16 queries per block; the batch's xyz staged once in LDS as float4
// (conflict-free ds_read_b128 in the scan) -- round 3 read global at 24B
// stride, which was TA/cache-line-bound.
// d2 in fp64 difference form (bit-robust true ranking; passed round 3).
// Top-32 as lane-distributed sorted list, lower-index tie-break.
// ---------------------------------------------------------------------------
__global__ __launch_bounds__(1024) void knn_kernel(const float* __restrict__ pc,
                                                   const int* __restrict__ rep,
                                                   float* __restrict__ out) {
    const int tid  = threadIdx.x;
    const int lane = tid & 63;
    const int w    = tid >> 6;
    const int q    = blockIdx.x * 16 + w;      // 16 queries/block, same batch
    const int b    = q >> 9;

    __shared__ float4 sp[NPTS];                // 128 KB

    const float* base = pc + (size_t)b * NPTS * 6;

#pragma unroll
    for (int j = 0; j < NPTS / 1024; ++j) {
        const int p = j * 1024 + tid;          // lane-consecutive: coalesced
        sp[p] = make_float4(base[p * 6 + 0], base[p * 6 + 1], base[p * 6 + 2], 0.0f);
    }
    __syncthreads();

    const int r = rep[q];
    const float4 Q = sp[r];
    const double qx = (double)Q.x, qy = (double)Q.y, qz = (double)Q.z;

    const double DINF = __longlong_as_double(0x7ff0000000000000LL);
    double vd = DINF;  int vi = 0x7fffffff;    // distributed sorted list entry
    double taud = DINF; int taui = 0x7fffffff; // current 32nd element (lane 31)

    for (int i = 0; i < NPTS / 64; ++i) {
        const int p = i * 64 + lane;
        const float4 T = sp[p];                // ds_read_b128, conflict-free
        const double dx = qx - (double)T.x;
        const double dy = qy - (double)T.y;
        const double dz = qz - (double)T.z;
        const double d2 = dx * dx + dy * dy + dz * dz;   // no cancellation

        const bool acc = (d2 < taud) || (d2 == taud && p < taui);
        unsigned long long mask = __ballot(acc);
        while (mask) {
            const int l = __ffsll(mask) - 1;
            mask &= mask - 1;
            const double xd = __shfl(d2, l);
            const int    xi = __shfl(p, l);
            const double pd = __shfl_up(vd, 1);
            const int    pi = __shfl_up(vi, 1);
            const bool ltp = (lane > 0) && ((xd < pd) || (xd == pd && xi < pi));
            const bool ltc = (xd < vd) || (xd == vd && xi < vi);
            const double nvd = ltp ? pd : (ltc ? xd : vd);
            const int    nvi = ltp ? pi : (ltc ? xi : vi);
            vd = nvd; vi = nvi;
        }
        taud = __shfl(vd, 31);
        taui = __shfl(vi, 31);
    }

    // ---- outputs ----
    const size_t NBH = (size_t)NBATCH * NGROUP * GSIZE * 6;   // neighborhood elems
    const size_t CEN = (size_t)NBATCH * NGROUP * 6;           // center elems

    if (lane == 0) {
#pragma unroll
        for (int c = 0; c < 6; ++c)
            out[NBH + (size_t)q * 6 + c] = base[r * 6 + c];
    }
    if (lane < GSIZE) {
        const int n = vi;                      // lane-sorted: position == lane
        out[NBH + CEN + (size_t)q * GSIZE + lane] = (float)n;

        const float* np_ = base + (size_t)n * 6;
        const size_t o = ((size_t)q * GSIZE + lane) * 6;
        out[o + 0] = __fsub_rn(np_[0], Q.x);
        out[o + 1] = __fsub_rn(np_[1], Q.y);
        out[o + 2] = __fsub_rn(np_[2], Q.z);
        out[o + 3] = np_[3];
        out[o + 4] = np_[4];
        out[o + 5] = np_[5];
    }
}

extern "C" void kernel_launch(void* const* d_in, const int* in_sizes, int n_in,
                              void* d_out, int out_size, void* d_ws, size_t ws_size,
                              hipStream_t stream) {
    const float* pc  = (const float*)d_in[0];
    float*       out = (float*)d_out;
    int*         rep = (int*)d_ws;             // 16*512 ints = 32 KB scratch

    fps_kernel<<<NBATCH, 512, 0, stream>>>(pc, rep);
    knn_kernel<<<NBATCH * NGROUP / 16, 1024, 0, stream>>>(pc, rep, out);
}

// Round 6
// 722.122 us; speedup vs baseline: 1.4339x; 1.0512x over previous
//
#include <hip/hip_runtime.h>

#define NPTS   8192
#define NBATCH 16
#define NGROUP 512
#define GSIZE  32
#define BIGF   1e10f

typedef unsigned long long u64;

// DPP max on a packed u64 key: shift both 32-bit halves with the same ctrl,
// compare-select. CTRL must be an ICE. bound_ctrl=true injects key=0
// (val=0.0, enc-idx=0 i.e. idx 8191) which loses every comparison against a
// real candidate (distinct indices -> distinct keys, val>=0), so it's inert.
template <int CTRL>
__device__ __forceinline__ u64 dpp_max_u64(u64 k) {
    const unsigned lo  = (unsigned)k;
    const unsigned hi  = (unsigned)(k >> 32);
    const unsigned slo = (unsigned)__builtin_amdgcn_update_dpp(0, (int)lo, CTRL, 0xF, 0xF, true);
    const unsigned shi = (unsigned)__builtin_amdgcn_update_dpp(0, (int)hi, CTRL, 0xF, 0xF, true);
    const u64 s = ((u64)shi << 32) | slo;
    return s > k ? s : k;
}

__device__ __forceinline__ u64 umax64(u64 a, u64 b) { return a > b ? a : b; }

// ---------------------------------------------------------------------------
// Prepack: xyz of every point as float4 (one coalesced 16B load in knn).
// ---------------------------------------------------------------------------
__global__ __launch_bounds__(256) void prepack_kernel(const float* __restrict__ pc,
                                                      float4* __restrict__ ws4) {
    const int i = blockIdx.x * 256 + threadIdx.x;     // 0 .. 131071
    const float* s = pc + (size_t)i * 6;
    ws4[i] = make_float4(s[0], s[1], s[2], 0.0f);
}

// ---------------------------------------------------------------------------
// Kernel 1: farthest point sampling. One block per batch, 512 threads
// (8 waves), 16 points per thread in registers; coords in LDS float4 for the
// broadcast read of the selected point.
// Wave argmax: packed u64 key (bits(val)<<13)|(8191-idx) reduced entirely in
// the DPP butterfly (row_shr 1/2/4/8 + row_bcast 15/31) -> lane 63 holds the
// wave winner; NO cross-lane shuffles in the serial tail. Max over keys ==
// (max value, then lowest index) — identical selection to jnp.argmax.
// Cross-wave: 8 u64 keys in LDS, pairwise-tree max (depth 3).
// ---------------------------------------------------------------------------
__global__ __launch_bounds__(512) void fps_kernel(const float* __restrict__ pc,
                                                  int* __restrict__ rep) {
    const int b    = blockIdx.x;
    const int t    = threadIdx.x;
    const int lane = t & 63;
    const int w    = t >> 6;

    __shared__ float4 sp[NPTS];                      // 128 KB
    __shared__ u64 keys[2][8];

    const float* base = pc + (size_t)b * NPTS * 6;

    float px[16], py[16], pz[16], dmin[16];
#pragma unroll
    for (int j = 0; j < 16; ++j) {
        const int p = t * 16 + j;
        const float x = base[p * 6 + 0];
        const float y = base[p * 6 + 1];
        const float z = base[p * 6 + 2];
        px[j] = x; py[j] = y; pz[j] = z;
        sp[p] = make_float4(x, y, z, 0.0f);
        dmin[j] = BIGF;
    }
    __syncthreads();

    int last = 0;
    for (int k = 0; k < NGROUP; ++k) {
        if (t == 0) rep[b * NGROUP + k] = last;
        if (k == NGROUP - 1) break;

        const float4 L = sp[last];                   // one ds_read_b128, broadcast

        float bv = -1.0f;
        int   bi = 0;
#pragma unroll
        for (int j = 0; j < 16; ++j) {
            const float dx = __fsub_rn(px[j], L.x);
            const float dy = __fsub_rn(py[j], L.y);
            const float dz = __fsub_rn(pz[j], L.z);
            // ((dx^2 + dy^2) + dz^2), no FMA -> matches numpy fp32 (verified)
            const float d = __fadd_rn(__fadd_rn(__fmul_rn(dx, dx),
                                                __fmul_rn(dy, dy)),
                                      __fmul_rn(dz, dz));
            const float dm = fminf(dmin[j], d);
            dmin[j] = dm;
            if (dm > bv) { bv = dm; bi = t * 16 + j; }   // strict > keeps lowest idx
        }

        // pack once, reduce packed key via DPP (no shuffles, no ballot)
        u64 key = ((u64)__float_as_uint(bv) << 13) | (unsigned)(8191 - bi);
        key = dpp_max_u64<0x111>(key);   // row_shr:1
        key = dpp_max_u64<0x112>(key);   // row_shr:2
        key = dpp_max_u64<0x114>(key);   // row_shr:4
        key = dpp_max_u64<0x118>(key);   // row_shr:8
        key = dpp_max_u64<0x142>(key);   // row_bcast:15
        key = dpp_max_u64<0x143>(key);   // row_bcast:31 -> lane 63 = wave max

        const int buf = k & 1;                       // parity dbuf -> 1 barrier/iter
        if (lane == 63) keys[buf][w] = key;
        __syncthreads();

        const u64* kb = keys[buf];                   // 8 broadcast b64 reads, tree max
        const u64 m0 = umax64(kb[0], kb[1]);
        const u64 m1 = umax64(kb[2], kb[3]);
        const u64 m2 = umax64(kb[4], kb[5]);
        const u64 m3 = umax64(kb[6], kb[7]);
        const u64 best = umax64(umax64(m0, m1), umax64(m2, m3));
        last = 8191 - (int)(best & 0x1FFFull);
    }
}

// ---------------------------------------------------------------------------
// Kernel 2: 32-NN per sampled center + gathers. One wave per query,
// 256-thread blocks (round-3 structure: beat the 128KB-LDS variant).
// USE4=1: scan reads prepacked float4 (coalesced 16B, L2-resident).
// d2 in fp64 difference form (bit-robust true ranking; passed rounds 3/5).
// Top-32 as lane-distributed sorted list, lower-index tie-break.
// tau broadcast skipped on iterations with no accepts (wave-uniform guard).
// ---------------------------------------------------------------------------
template <int USE4>
__global__ __launch_bounds__(256) void knn_kernel(const float* __restrict__ pc,
                                                  const float4* __restrict__ ws4,
                                                  const int* __restrict__ rep,
                                                  float* __restrict__ out) {
    const int tid  = threadIdx.x;
    const int lane = tid & 63;
    const int w    = tid >> 6;
    const int q    = blockIdx.x * 4 + w;       // 0 .. 8191
    const int b    = q >> 9;

    const float*  base  = pc  + (size_t)b * NPTS * 6;
    const float4* base4 = ws4 + ((size_t)b << 13);
    const int     r     = rep[q];

    float qxf, qyf, qzf;
    if (USE4) {
        const float4 Q = base4[r];
        qxf = Q.x; qyf = Q.y; qzf = Q.z;
    } else {
        qxf = base[r * 6 + 0]; qyf = base[r * 6 + 1]; qzf = base[r * 6 + 2];
    }
    const double qx = (double)qxf, qy = (double)qyf, qz = (double)qzf;

    const double DINF = __longlong_as_double(0x7ff0000000000000LL);
    double vd = DINF;  int vi = 0x7fffffff;    // distributed sorted list entry
    double taud = DINF; int taui = 0x7fffffff; // current 32nd element (lane 31)

    for (int i = 0; i < NPTS / 64; ++i) {
        const int p = i * 64 + lane;
        float tx, ty, tz;
        if (USE4) {
            const float4 T = base4[p];         // coalesced 16B
            tx = T.x; ty = T.y; tz = T.z;
        } else {
            tx = base[p * 6 + 0]; ty = base[p * 6 + 1]; tz = base[p * 6 + 2];
        }
        const double dx = qx - (double)tx;
        const double dy = qy - (double)ty;
        const double dz = qz - (double)tz;
        const double d2 = dx * dx + dy * dy + dz * dz;   // no cancellation

        const bool acc = (d2 < taud) || (d2 == taud && p < taui);
        const unsigned long long mask0 = __ballot(acc);
        unsigned long long mask = mask0;
        while (mask) {
            const int l = __ffsll(mask) - 1;
            mask &= mask - 1;
            const double xd = __shfl(d2, l);
            const int    xi = __shfl(p, l);
            const double pd = __shfl_up(vd, 1);
            const int    pi = __shfl_up(vi, 1);
            const bool ltp = (lane > 0) && ((xd < pd) || (xd == pd && xi < pi));
            const bool ltc = (xd < vd) || (xd == vd && xi < vi);
            const double nvd = ltp ? pd : (ltc ? xd : vd);
            const int    nvi = ltp ? pi : (ltc ? xi : vi);
            vd = nvd; vi = nvi;
        }
        if (mask0) {                           // wave-uniform: tau unchanged if no accept
            taud = __shfl(vd, 31);
            taui = __shfl(vi, 31);
        }
    }

    // ---- outputs ----
    const size_t NBH = (size_t)NBATCH * NGROUP * GSIZE * 6;   // neighborhood elems
    const size_t CEN = (size_t)NBATCH * NGROUP * 6;           // center elems

    if (lane == 0) {
#pragma unroll
        for (int c = 0; c < 6; ++c)
            out[NBH + (size_t)q * 6 + c] = base[r * 6 + c];
    }
    if (lane < GSIZE) {
        const int n = vi;                      // lane-sorted: position == lane
        out[NBH + CEN + (size_t)q * GSIZE + lane] = (float)n;

        const float* np_ = base + (size_t)n * 6;
        const size_t o = ((size_t)q * GSIZE + lane) * 6;
        out[o + 0] = __fsub_rn(np_[0], qxf);
        out[o + 1] = __fsub_rn(np_[1], qyf);
        out[o + 2] = __fsub_rn(np_[2], qzf);
        out[o + 3] = np_[3];
        out[o + 4] = np_[4];
        out[o + 5] = np_[5];
    }
}

extern "C" void kernel_launch(void* const* d_in, const int* in_sizes, int n_in,
                              void* d_out, int out_size, void* d_ws, size_t ws_size,
                              hipStream_t stream) {
    const float* pc  = (const float*)d_in[0];
    float*       out = (float*)d_out;
    int*         rep = (int*)d_ws;                              // 32 KB
    float4*      ws4 = (float4*)((char*)d_ws + 32 * 1024);      // 2 MB

    const bool use4 = ws_size >= (size_t)32 * 1024 + sizeof(float4) * NBATCH * NPTS;

    if (use4)
        prepack_kernel<<<NBATCH * NPTS / 256, 256, 0, stream>>>(pc, ws4);
    fps_kernel<<<NBATCH, 512, 0, stream>>>(pc, rep);
    if (use4)
        knn_kernel<1><<<NBATCH * NGROUP / 4, 256, 0, stream>>>(pc, ws4, rep, out);
    else
        knn_kernel<0><<<NBATCH * NGROUP / 4, 256, 0, stream>>>(pc, ws4, rep, out);
}

// Round 7
// 721.318 us; speedup vs baseline: 1.4355x; 1.0011x over previous
//
#include <hip/hip_runtime.h>

#define NPTS   8192
#define NBATCH 16
#define NGROUP 512
#define GSIZE  32
#define BIGF   1e10f

typedef unsigned long long u64;
typedef float f32x2 __attribute__((ext_vector_type(2)));

// DPP max on a packed u64 key: shift both 32-bit halves with the same ctrl,
// compare-select. CTRL must be an ICE. bound_ctrl=true injects key=0
// (val=0.0, enc-idx=0 i.e. idx 8191) which loses every comparison against a
// real candidate (distinct indices -> distinct keys, val>=0), so it's inert.
template <int CTRL>
__device__ __forceinline__ u64 dpp_max_u64(u64 k) {
    const unsigned lo  = (unsigned)k;
    const unsigned hi  = (unsigned)(k >> 32);
    const unsigned slo = (unsigned)__builtin_amdgcn_update_dpp(0, (int)lo, CTRL, 0xF, 0xF, true);
    const unsigned shi = (unsigned)__builtin_amdgcn_update_dpp(0, (int)hi, CTRL, 0xF, 0xF, true);
    const u64 s = ((u64)shi << 32) | slo;
    return s > k ? s : k;
}

__device__ __forceinline__ u64 umax64(u64 a, u64 b) { return a > b ? a : b; }

// ---------------------------------------------------------------------------
// Prepack: xyz of every point as float4 (one coalesced 16B load in knn).
// ---------------------------------------------------------------------------
__global__ __launch_bounds__(256) void prepack_kernel(const float* __restrict__ pc,
                                                      float4* __restrict__ ws4) {
    const int i = blockIdx.x * 256 + threadIdx.x;     // 0 .. 131071
    const float* s = pc + (size_t)i * 6;
    ws4[i] = make_float4(s[0], s[1], s[2], 0.0f);
}

// ---------------------------------------------------------------------------
// Kernel 1: farthest point sampling. One block per batch, 512 threads
// (8 waves), 16 points per thread (as 8 x float2) in registers; coords in LDS
// float4 for the broadcast read of the selected point.
// - Dist math in PACKED fp32 (v_pk_add/mul_f32): same IEEE-rn ops, half the
//   issue slots. contract(off) forbids pk-FMA fusion -> bits identical to the
//   scalar ((dx^2+dy^2)+dz^2) sequence that passed rounds 3/5/6.
// - NO global stores inside the serial loop (rep buffered in LDS): the
//   compiler's s_waitcnt vmcnt(0) before each s_barrier was draining wave 0's
//   rep store through L2 every iteration.
// - Wave argmax: packed u64 key (bits(val)<<13)|(8191-idx) reduced in the DPP
//   butterfly; lane 63 holds the wave winner. Max over keys == (max value,
//   lowest index) — identical selection to jnp.argmax.
// - Cross-wave: 8 u64 keys in LDS read as 4x ulonglong2 (b128), tree max.
// ---------------------------------------------------------------------------
__global__ __launch_bounds__(512) void fps_kernel(const float* __restrict__ pc,
                                                  int* __restrict__ rep) {
#pragma clang fp contract(off)
    const int b    = blockIdx.x;
    const int t    = threadIdx.x;
    const int lane = t & 63;
    const int w    = t >> 6;

    __shared__ float4 sp[NPTS];                      // 128 KB
    __shared__ __align__(16) u64 keys[2][8];
    __shared__ int lrep[NGROUP];                     // 2 KB

    const float* base = pc + (size_t)b * NPTS * 6;

    f32x2 px[8], py[8], pz[8], dmin[8];
#pragma unroll
    for (int j = 0; j < 8; ++j) {
        const int p0 = t * 16 + 2 * j;
        const int p1 = p0 + 1;
        const float x0 = base[p0 * 6 + 0], y0 = base[p0 * 6 + 1], z0 = base[p0 * 6 + 2];
        const float x1 = base[p1 * 6 + 0], y1 = base[p1 * 6 + 1], z1 = base[p1 * 6 + 2];
        px[j] = (f32x2){x0, x1};
        py[j] = (f32x2){y0, y1};
        pz[j] = (f32x2){z0, z1};
        sp[p0] = make_float4(x0, y0, z0, 0.0f);
        sp[p1] = make_float4(x1, y1, z1, 0.0f);
        dmin[j] = (f32x2){BIGF, BIGF};
    }
    __syncthreads();

    int last = 0;
    for (int k = 0; k < NGROUP; ++k) {
        if (t == 0) lrep[k] = last;                  // LDS, not global
        if (k == NGROUP - 1) break;

        const float4 L = sp[last];                   // one ds_read_b128, broadcast
        const f32x2 Lx = (f32x2){L.x, L.x};
        const f32x2 Ly = (f32x2){L.y, L.y};
        const f32x2 Lz = (f32x2){L.z, L.z};

        float bv = -1.0f;
        int   bi = 0;
#pragma unroll
        for (int j = 0; j < 8; ++j) {
            const f32x2 dx = px[j] - Lx;             // v_pk_add_f32 (sub)
            const f32x2 dy = py[j] - Ly;
            const f32x2 dz = pz[j] - Lz;
            const f32x2 qx = dx * dx;                // v_pk_mul_f32
            const f32x2 qy = dy * dy;
            const f32x2 qz = dz * dz;
            const f32x2 d  = (qx + qy) + qz;         // v_pk_add_f32, no FMA
            f32x2 dm;
            dm.x = fminf(dmin[j].x, d.x);
            dm.y = fminf(dmin[j].y, d.y);
            dmin[j] = dm;
            if (dm.x > bv) { bv = dm.x; bi = t * 16 + 2 * j; }      // strict >
            if (dm.y > bv) { bv = dm.y; bi = t * 16 + 2 * j + 1; }  // keeps lowest idx
        }

        // pack once, reduce packed key via DPP (no shuffles, no ballot)
        u64 key = ((u64)__float_as_uint(bv) << 13) | (unsigned)(8191 - bi);
        key = dpp_max_u64<0x111>(key);   // row_shr:1
        key = dpp_max_u64<0x112>(key);   // row_shr:2
        key = dpp_max_u64<0x114>(key);   // row_shr:4
        key = dpp_max_u64<0x118>(key);   // row_shr:8
        key = dpp_max_u64<0x142>(key);   // row_bcast:15
        key = dpp_max_u64<0x143>(key);   // row_bcast:31 -> lane 63 = wave max

        const int buf = k & 1;                       // parity dbuf -> 1 barrier/iter
        if (lane == 63) keys[buf][w] = key;
        __syncthreads();

        const ulonglong2* kp = (const ulonglong2*)keys[buf];   // 4x ds_read_b128
        const ulonglong2 k0 = kp[0], k1 = kp[1], k2 = kp[2], k3 = kp[3];
        const u64 best = umax64(umax64(umax64(k0.x, k0.y), umax64(k1.x, k1.y)),
                                umax64(umax64(k2.x, k2.y), umax64(k3.x, k3.y)));
        last = 8191 - (int)(best & 0x1FFFull);
    }

    __syncthreads();                                 // lrep[511] visibility
    for (int j = t; j < NGROUP; j += 512)            // one coalesced write-out
        rep[b * NGROUP + j] = lrep[j];
}

// ---------------------------------------------------------------------------
// Kernel 2: 32-NN per sampled center + gathers. One wave per query,
// 256-thread blocks. Scan reads prepacked float4 (coalesced 16B, L2-resident).
// d2 in fp64 difference form (bit-robust true ranking; passed rounds 3/5/6).
// Top-32 as lane-distributed sorted list, lower-index tie-break.
// tau broadcast skipped on iterations with no accepts (wave-uniform guard).
// (Unchanged from round 6 — control while fps is the dominant dispatch.)
// ---------------------------------------------------------------------------
__global__ __launch_bounds__(256) void knn_kernel(const float* __restrict__ pc,
                                                  const float4* __restrict__ ws4,
                                                  const int* __restrict__ rep,
                                                  float* __restrict__ out) {
    const int tid  = threadIdx.x;
    const int lane = tid & 63;
    const int w    = tid >> 6;
    const int q    = blockIdx.x * 4 + w;       // 0 .. 8191
    const int b    = q >> 9;

    const float*  base  = pc  + (size_t)b * NPTS * 6;
    const float4* base4 = ws4 + ((size_t)b << 13);
    const int     r     = rep[q];

    const float4 Q = base4[r];
    const float qxf = Q.x, qyf = Q.y, qzf = Q.z;
    const double qx = (double)qxf, qy = (double)qyf, qz = (double)qzf;

    const double DINF = __longlong_as_double(0x7ff0000000000000LL);
    double vd = DINF;  int vi = 0x7fffffff;    // distributed sorted list entry
    double taud = DINF; int taui = 0x7fffffff; // current 32nd element (lane 31)

    for (int i = 0; i < NPTS / 64; ++i) {
        const int p = i * 64 + lane;
        const float4 T = base4[p];             // coalesced 16B
        const double dx = qx - (double)T.x;
        const double dy = qy - (double)T.y;
        const double dz = qz - (double)T.z;
        const double d2 = dx * dx + dy * dy + dz * dz;   // no cancellation

        const bool acc = (d2 < taud) || (d2 == taud && p < taui);
        const unsigned long long mask0 = __ballot(acc);
        unsigned long long mask = mask0;
        while (mask) {
            const int l = __ffsll(mask) - 1;
            mask &= mask - 1;
            const double xd = __shfl(d2, l);
            const int    xi = __shfl(p, l);
            const double pd = __shfl_up(vd, 1);
            const int    pi = __shfl_up(vi, 1);
            const bool ltp = (lane > 0) && ((xd < pd) || (xd == pd && xi < pi));
            const bool ltc = (xd < vd) || (xd == vd && xi < vi);
            const double nvd = ltp ? pd : (ltc ? xd : vd);
            const int    nvi = ltp ? pi : (ltc ? xi : vi);
            vd = nvd; vi = nvi;
        }
        if (mask0) {                           // wave-uniform: tau unchanged if no accept
            taud = __shfl(vd, 31);
            taui = __shfl(vi, 31);
        }
    }

    // ---- outputs ----
    const size_t NBH = (size_t)NBATCH * NGROUP * GSIZE * 6;   // neighborhood elems
    const size_t CEN = (size_t)NBATCH * NGROUP * 6;           // center elems

    if (lane == 0) {
#pragma unroll
        for (int c = 0; c < 6; ++c)
            out[NBH + (size_t)q * 6 + c] = base[r * 6 + c];
    }
    if (lane < GSIZE) {
        const int n = vi;                      // lane-sorted: position == lane
        out[NBH + CEN + (size_t)q * GSIZE + lane] = (float)n;

        const float* np_ = base + (size_t)n * 6;
        const size_t o = ((size_t)q * GSIZE + lane) * 6;
        out[o + 0] = __fsub_rn(np_[0], qxf);
        out[o + 1] = __fsub_rn(np_[1], qyf);
        out[o + 2] = __fsub_rn(np_[2], qzf);
        out[o + 3] = np_[3];
        out[o + 4] = np_[4];
        out[o + 5] = np_[5];
    }
}

extern "C" void kernel_launch(void* const* d_in, const int* in_sizes, int n_in,
                              void* d_out, int out_size, void* d_ws, size_t ws_size,
                              hipStream_t stream) {
    const float* pc  = (const float*)d_in[0];
    float*       out = (float*)d_out;
    int*         rep = (int*)d_ws;                              // 32 KB
    float4*      ws4 = (float4*)((char*)d_ws + 32 * 1024);      // 2 MB

    prepack_kernel<<<NBATCH * NPTS / 256, 256, 0, stream>>>(pc, ws4);
    fps_kernel<<<NBATCH, 512, 0, stream>>>(pc, rep);
    knn_kernel<<<NBATCH * NGROUP / 4, 256, 0, stream>>>(pc, ws4, rep, out);
}